// Round 1
// baseline (1564.564 us; speedup 1.0000x reference)
//
#include <hip/hip_runtime.h>

#define N_NODES 20000
#define N_EDGES 320000
#define F_IN 512
#define F_OUT 1024
#define N_GRAPHS 64

// ---------------- degree / dinv ----------------
__global__ void k_init(float* deg, int* cnt, int* cursor) {
    int i = blockIdx.x * 256 + threadIdx.x;
    if (i < N_NODES) { deg[i] = 1.0f; cnt[i] = 0; cursor[i] = 0; }
}

__global__ void k_deg(const int* __restrict__ dst, const float* __restrict__ ew,
                      float* deg, int* cnt) {
    int e = blockIdx.x * 256 + threadIdx.x;
    if (e < N_EDGES) {
        int d = dst[e];
        atomicAdd(&deg[d], ew[e]);
        atomicAdd(&cnt[d], 1);
    }
}

__global__ void k_dinv(float* deg) {
    int i = blockIdx.x * 256 + threadIdx.x;
    if (i < N_NODES) deg[i] = rsqrtf(deg[i]);  // deg >= 1 always (self loop)
}

// ---------------- CSR build ----------------
__global__ __launch_bounds__(1024) void k_scan(const int* __restrict__ cnt, int* offs) {
    __shared__ int s[1024];
    int t = threadIdx.x;
    const int CH = (N_NODES + 1023) / 1024;  // 20
    int lo = t * CH, hi = min(lo + CH, N_NODES);
    int sum = 0;
    for (int i = lo; i < hi; i++) sum += cnt[i];
    s[t] = sum;
    __syncthreads();
    for (int off = 1; off < 1024; off <<= 1) {
        int v = (t >= off) ? s[t - off] : 0;
        __syncthreads();
        s[t] += v;
        __syncthreads();
    }
    int run = (t == 0) ? 0 : s[t - 1];
    for (int i = lo; i < hi; i++) { offs[i] = run; run += cnt[i]; }
    if (hi == N_NODES && lo < N_NODES) offs[N_NODES] = run;
}

__global__ void k_fill(const int* __restrict__ src, const int* __restrict__ dst,
                       const float* __restrict__ ew, const float* __restrict__ dinv,
                       const int* __restrict__ offs, int* cursor,
                       int* csr_src, float* csr_w) {
    int e = blockIdx.x * 256 + threadIdx.x;
    if (e < N_EDGES) {
        int d = dst[e], s = src[e];
        int pos = offs[d] + atomicAdd(&cursor[d], 1);
        csr_src[pos] = s;
        csr_w[pos] = dinv[s] * ew[e] * dinv[d];
    }
}

// ---------------- fp32 tiled GEMM: C[N,M] = A[N,K] @ B[K,M] ----------------
// BM=BN=64, BK=16, 256 threads, 4x4 microtile per thread.
__global__ __launch_bounds__(256) void k_gemm(const float* __restrict__ A,
                                              const float* __restrict__ B,
                                              float* __restrict__ C,
                                              int Nrows, int K, int M) {
    __shared__ float As[16][64];
    __shared__ float Bs[16][64];
    const int row0 = blockIdx.x * 64;
    const int col0 = blockIdx.y * 64;
    const int tid = threadIdx.x;
    const int tx = tid & 15, ty = tid >> 4;

    // A load: thread -> row = tid>>2 (0..63), k-quad = (tid&3)*4
    const int arow = tid >> 2, akq = (tid & 3) * 4;
    // B load: thread -> krow = tid>>4 (0..15), col-quad = (tid&15)*4
    const int brow = tid >> 4, bcol = (tid & 15) * 4;

    float acc[4][4] = {};

    for (int k0 = 0; k0 < K; k0 += 16) {
        float4 av;
        if (row0 + arow < Nrows)
            av = *(const float4*)&A[(size_t)(row0 + arow) * K + k0 + akq];
        else
            av = make_float4(0.f, 0.f, 0.f, 0.f);
        As[akq + 0][arow] = av.x;
        As[akq + 1][arow] = av.y;
        As[akq + 2][arow] = av.z;
        As[akq + 3][arow] = av.w;

        float4 bv = *(const float4*)&B[(size_t)(k0 + brow) * M + col0 + bcol];
        *(float4*)&Bs[brow][bcol] = bv;
        __syncthreads();

#pragma unroll
        for (int kk = 0; kk < 16; kk++) {
            float4 a = *(float4*)&As[kk][ty * 4];
            float4 b = *(float4*)&Bs[kk][tx * 4];
            acc[0][0] += a.x * b.x; acc[0][1] += a.x * b.y; acc[0][2] += a.x * b.z; acc[0][3] += a.x * b.w;
            acc[1][0] += a.y * b.x; acc[1][1] += a.y * b.y; acc[1][2] += a.y * b.z; acc[1][3] += a.y * b.w;
            acc[2][0] += a.z * b.x; acc[2][1] += a.z * b.y; acc[2][2] += a.z * b.z; acc[2][3] += a.z * b.w;
            acc[3][0] += a.w * b.x; acc[3][1] += a.w * b.y; acc[3][2] += a.w * b.z; acc[3][3] += a.w * b.w;
        }
        __syncthreads();
    }

#pragma unroll
    for (int i = 0; i < 4; i++) {
        int r = row0 + ty * 4 + i;
        if (r < Nrows) {
            *(float4*)&C[(size_t)r * M + col0 + tx * 4] =
                make_float4(acc[i][0], acc[i][1], acc[i][2], acc[i][3]);
        }
    }
}

// ---------------- aggregation: h[n] = relu(b + dinv[n]^2*xw[n] + sum_e w*xw[src]) ----------------
__global__ __launch_bounds__(256) void k_aggr(const float* __restrict__ xw,
                                              const float* __restrict__ dinv,
                                              const int* __restrict__ offs,
                                              const int* __restrict__ csr_src,
                                              const float* __restrict__ csr_w,
                                              const float* __restrict__ bias,
                                              float* __restrict__ h) {
    const int n = blockIdx.x;
    const int c = threadIdx.x * 4;  // 256 threads * 4 cols = 1024
    const float di = dinv[n];
    const float wself = di * di;

    float4 v = *(const float4*)&xw[(size_t)n * F_OUT + c];
    float ax = v.x * wself, ay = v.y * wself, az = v.z * wself, aw = v.w * wself;

    const int lo = offs[n], hi = offs[n + 1];
    for (int j = lo; j < hi; j++) {
        int s = csr_src[j];
        float w = csr_w[j];
        float4 u = *(const float4*)&xw[(size_t)s * F_OUT + c];
        ax += w * u.x; ay += w * u.y; az += w * u.z; aw += w * u.w;
    }
    float4 b = *(const float4*)&bias[c];
    ax += b.x; ay += b.y; az += b.z; aw += b.w;
    ax = fmaxf(ax, 0.f); ay = fmaxf(ay, 0.f); az = fmaxf(az, 0.f); aw = fmaxf(aw, 0.f);
    *(float4*)&h[(size_t)n * F_OUT + c] = make_float4(ax, ay, az, aw);
}

// ---------------- pooling ----------------
__global__ void k_gstart(const int* __restrict__ batch, int* gstart) {
    int g = threadIdx.x;
    if (g > N_GRAPHS) return;
    if (g == N_GRAPHS) { gstart[g] = N_NODES; return; }
    int lo = 0, hi = N_NODES;
    while (lo < hi) {
        int mid = (lo + hi) >> 1;
        if (batch[mid] < g) lo = mid + 1; else hi = mid;
    }
    gstart[g] = lo;
}

__global__ __launch_bounds__(64) void k_pool(const float* __restrict__ h,
                                             const int* __restrict__ gstart,
                                             float* __restrict__ out) {
    const int g = blockIdx.x;
    const int c = blockIdx.y * 256 + threadIdx.x * 4;
    const int lo = gstart[g], hi = gstart[g + 1];
    float ax = 0.f, ay = 0.f, az = 0.f, aw = 0.f;
    for (int n = lo; n < hi; n++) {
        float4 v = *(const float4*)&h[(size_t)n * F_OUT + c];
        ax += v.x; ay += v.y; az += v.z; aw += v.w;
    }
    float inv = 1.0f / (float)max(hi - lo, 1);
    *(float4*)&out[(size_t)g * F_OUT + c] = make_float4(ax * inv, ay * inv, az * inv, aw * inv);
}

// ---------------- launch ----------------
extern "C" void kernel_launch(void* const* d_in, const int* in_sizes, int n_in,
                              void* d_out, int out_size, void* d_ws, size_t ws_size,
                              hipStream_t stream) {
    const float* x    = (const float*)d_in[0];
    const int* ei     = (const int*)d_in[1];
    const float* ew   = (const float*)d_in[2];
    const int* batch  = (const int*)d_in[3];
    const float* W1   = (const float*)d_in[4];
    const float* b1   = (const float*)d_in[5];
    const float* W2   = (const float*)d_in[6];
    const float* b2   = (const float*)d_in[7];
    float* out = (float*)d_out;

    const int* src = ei;
    const int* dst = ei + N_EDGES;

    char* ws = (char*)d_ws;
    size_t off = 0;
    auto alloc = [&](size_t bytes) -> void* {
        void* p = ws + off;
        off += (bytes + 255) & ~(size_t)255;
        return p;
    };
    float* xw     = (float*)alloc((size_t)N_NODES * F_OUT * 4);
    float* h      = (float*)alloc((size_t)N_NODES * F_OUT * 4);
    float* dinv   = (float*)alloc((size_t)N_NODES * 4);   // starts as deg
    int*   cnt    = (int*)  alloc((size_t)N_NODES * 4);
    int*   offs   = (int*)  alloc((size_t)(N_NODES + 1) * 4);
    int*   cursor = (int*)  alloc((size_t)N_NODES * 4);
    int*   csrs   = (int*)  alloc((size_t)N_EDGES * 4);
    float* csrw   = (float*)alloc((size_t)N_EDGES * 4);
    int*   gstart = (int*)  alloc((size_t)(N_GRAPHS + 1) * 4);

    const int nb_n = (N_NODES + 255) / 256;
    const int nb_e = (N_EDGES + 255) / 256;

    k_init<<<nb_n, 256, 0, stream>>>(dinv, cnt, cursor);
    k_deg<<<nb_e, 256, 0, stream>>>(dst, ew, dinv, cnt);
    k_dinv<<<nb_n, 256, 0, stream>>>(dinv);
    k_scan<<<1, 1024, 0, stream>>>(cnt, offs);
    k_fill<<<nb_e, 256, 0, stream>>>(src, dst, ew, dinv, offs, cursor, csrs, csrw);
    k_gstart<<<1, 128, 0, stream>>>(batch, gstart);

    dim3 gg((N_NODES + 63) / 64, F_OUT / 64);
    // layer 1
    k_gemm<<<gg, 256, 0, stream>>>(x, W1, xw, N_NODES, F_IN, F_OUT);
    k_aggr<<<N_NODES, 256, 0, stream>>>(xw, dinv, offs, csrs, csrw, b1, h);
    // layer 2
    k_gemm<<<gg, 256, 0, stream>>>(h, W2, xw, N_NODES, F_OUT, F_OUT);
    k_aggr<<<N_NODES, 256, 0, stream>>>(xw, dinv, offs, csrs, csrw, b2, h);
    // pool
    dim3 gp(N_GRAPHS, F_OUT / 256);
    k_pool<<<gp, 64, 0, stream>>>(h, gstart, out);
}

// Round 2
// 769.119 us; speedup vs baseline: 2.0342x; 2.0342x over previous
//
#include <hip/hip_runtime.h>

#define N_NODES 20000
#define N_PAD   20096   // next multiple of 128
#define N_EDGES 320000
#define F_IN 512
#define F_OUT 1024
#define N_GRAPHS 64

typedef __attribute__((ext_vector_type(8))) short bf16x8;
typedef __attribute__((ext_vector_type(4))) float f32x4;
typedef __attribute__((ext_vector_type(8))) unsigned short ushort8v;

static __device__ __forceinline__ unsigned short f2bf(float f) {
    unsigned int u = __float_as_uint(f);
    u = (u + 0x7fff + ((u >> 16) & 1)) >> 16;   // RNE
    return (unsigned short)u;
}
static __device__ __forceinline__ float bf2f(unsigned short s) {
    return __uint_as_float(((unsigned int)s) << 16);
}

// ---------------- degree / dinv ----------------
__global__ void k_init(float* deg, int* cnt, int* cursor) {
    int i = blockIdx.x * 256 + threadIdx.x;
    if (i < N_NODES) { deg[i] = 1.0f; cnt[i] = 0; cursor[i] = 0; }
}

__global__ void k_deg(const int* __restrict__ dst, const float* __restrict__ ew,
                      float* deg, int* cnt) {
    int e = blockIdx.x * 256 + threadIdx.x;
    if (e < N_EDGES) {
        int d = dst[e];
        atomicAdd(&deg[d], ew[e]);
        atomicAdd(&cnt[d], 1);
    }
}

__global__ void k_dinv(float* deg) {
    int i = blockIdx.x * 256 + threadIdx.x;
    if (i < N_NODES) deg[i] = rsqrtf(deg[i]);
}

// ---------------- CSR build ----------------
__global__ __launch_bounds__(1024) void k_scan(const int* __restrict__ cnt, int* offs) {
    __shared__ int s[1024];
    int t = threadIdx.x;
    const int CH = (N_NODES + 1023) / 1024;
    int lo = t * CH, hi = min(lo + CH, N_NODES);
    int sum = 0;
    for (int i = lo; i < hi; i++) sum += cnt[i];
    s[t] = sum;
    __syncthreads();
    for (int off = 1; off < 1024; off <<= 1) {
        int v = (t >= off) ? s[t - off] : 0;
        __syncthreads();
        s[t] += v;
        __syncthreads();
    }
    int run = (t == 0) ? 0 : s[t - 1];
    for (int i = lo; i < hi; i++) { offs[i] = run; run += cnt[i]; }
    if (hi == N_NODES && lo < N_NODES) offs[N_NODES] = run;
}

__global__ void k_fill(const int* __restrict__ src, const int* __restrict__ dst,
                       const float* __restrict__ ew, const float* __restrict__ dinv,
                       const int* __restrict__ offs, int* cursor,
                       int* csr_src, float* csr_w) {
    int e = blockIdx.x * 256 + threadIdx.x;
    if (e < N_EDGES) {
        int d = dst[e], s = src[e];
        int pos = offs[d] + atomicAdd(&cursor[d], 1);
        csr_src[pos] = s;
        csr_w[pos] = dinv[s] * ew[e] * dinv[d];
    }
}

// ---------------- conversions ----------------
// x [20000][512] f32 -> xb [20096][512] bf16 (pad rows zero)
__global__ void k_conv_x(const float* __restrict__ x, unsigned short* __restrict__ xb) {
    int idx = blockIdx.x * 256 + threadIdx.x;      // one thread = 8 cols
    int row = idx >> 6;                             // 64 chunks/row
    int c8 = (idx & 63) * 8;
    if (row >= N_PAD) return;
    ushort8v v;
    if (row < N_NODES) {
        const float* p = &x[(size_t)row * F_IN + c8];
#pragma unroll
        for (int i = 0; i < 8; i++) v[i] = f2bf(p[i]);
    } else {
#pragma unroll
        for (int i = 0; i < 8; i++) v[i] = 0;
    }
    *(ushort8v*)&xb[(size_t)row * F_IN + c8] = v;
}

// W [K][1024] f32 -> Wt [1024][K] bf16 (tiled transpose)
__global__ __launch_bounds__(256) void k_conv_wt(const float* __restrict__ W,
                                                 unsigned short* __restrict__ Wt, int K) {
    __shared__ float tile[32][33];
    int n0 = blockIdx.x * 32;
    int k0 = blockIdx.y * 32;
    int tx = threadIdx.x & 31;
    int ty = threadIdx.x >> 5;   // 0..7
#pragma unroll
    for (int i = 0; i < 32; i += 8)
        tile[ty + i][tx] = W[(size_t)(k0 + ty + i) * F_OUT + n0 + tx];
    __syncthreads();
#pragma unroll
    for (int i = 0; i < 32; i += 8)
        Wt[(size_t)(n0 + ty + i) * K + k0 + tx] = f2bf(tile[tx][ty + i]);
}

// ---------------- bf16 MFMA GEMM: C[Mpad,1024] = A[Mpad,K] @ Bt[1024,K]^T ----------------
// BM=BN=128, BK=32, 256 threads (4 waves in 2x2), 4x4 16x16x32 MFMA per wave.
__global__ __launch_bounds__(256) void k_gemm_bf16(const unsigned short* __restrict__ A,
                                                   const unsigned short* __restrict__ Bt,
                                                   float* __restrict__ C, int K) {
    __shared__ short As[128 * 32];   // 8 KB
    __shared__ short Bs[128 * 32];   // 8 KB (tile of Bt: 128 n-rows x 32 k)
    const int tid = threadIdx.x;
    const int lane = tid & 63;
    const int wave = tid >> 6;
    const int wm = wave >> 1, wn = wave & 1;   // 2x2 wave grid, 64x64 each
    const int row0 = blockIdx.x * 128;
    const int col0 = blockIdx.y * 128;
    const int fl = lane & 15;       // A-row / B-col / D-col
    const int fq = lane >> 4;       // quad

    f32x4 acc[4][4] = {};

    for (int k0 = 0; k0 < K; k0 += 32) {
        // stage A tile [128][32] and B tile [128][32], 16B/lane direct-to-LDS
#pragma unroll
        for (int it = 0; it < 2; it++) {
            int idx = it * 256 + tid;           // 0..511 chunk id
            int r = idx >> 2, k8 = (idx & 3) * 8;
            const unsigned short* ga = &A[(size_t)(row0 + r) * K + k0 + k8];
            __builtin_amdgcn_global_load_lds(
                (const __attribute__((address_space(1))) void*)ga,
                (__attribute__((address_space(3))) void*)&As[idx * 8], 16, 0, 0);
            const unsigned short* gb = &Bt[(size_t)(col0 + r) * K + k0 + k8];
            __builtin_amdgcn_global_load_lds(
                (const __attribute__((address_space(1))) void*)gb,
                (__attribute__((address_space(3))) void*)&Bs[idx * 8], 16, 0, 0);
        }
        __syncthreads();

        bf16x8 af[4], bf[4];
#pragma unroll
        for (int i = 0; i < 4; i++)
            af[i] = *(const bf16x8*)&As[(wm * 64 + i * 16 + fl) * 32 + fq * 8];
#pragma unroll
        for (int j = 0; j < 4; j++)
            bf[j] = *(const bf16x8*)&Bs[(wn * 64 + j * 16 + fl) * 32 + fq * 8];
#pragma unroll
        for (int i = 0; i < 4; i++)
#pragma unroll
            for (int j = 0; j < 4; j++)
                acc[i][j] = __builtin_amdgcn_mfma_f32_16x16x32_bf16(af[i], bf[j], acc[i][j], 0, 0, 0);
        __syncthreads();
    }

    // D layout: col = lane&15, row = quad*4 + reg  [m89/m91]
#pragma unroll
    for (int i = 0; i < 4; i++) {
#pragma unroll
        for (int j = 0; j < 4; j++) {
            int rbase = row0 + wm * 64 + i * 16 + fq * 4;
            int c = col0 + wn * 64 + j * 16 + fl;
#pragma unroll
            for (int r = 0; r < 4; r++)
                C[(size_t)(rbase + r) * F_OUT + c] = acc[i][j][r];
        }
    }
}

// ---------------- aggregation: out_bf16[n] = relu(b + dinv^2*xw[n] + sum w*xw[src]) ----------------
__global__ __launch_bounds__(256) void k_aggr_bf16(const float* __restrict__ xw,
                                                   const float* __restrict__ dinv,
                                                   const int* __restrict__ offs,
                                                   const int* __restrict__ csr_src,
                                                   const float* __restrict__ csr_w,
                                                   const float* __restrict__ bias,
                                                   unsigned short* __restrict__ out) {
    const int n = blockIdx.x;
    const int c = threadIdx.x * 4;
    if (n >= N_NODES) {   // zero pad rows (GEMM2 A-tile reads them)
        *(ushort4*)&out[(size_t)n * F_OUT + c] = make_ushort4(0, 0, 0, 0);
        return;
    }
    const float di = dinv[n];
    const float wself = di * di;

    float4 v = *(const float4*)&xw[(size_t)n * F_OUT + c];
    float ax = v.x * wself, ay = v.y * wself, az = v.z * wself, aw = v.w * wself;

    const int lo = offs[n], hi = offs[n + 1];
    for (int j = lo; j < hi; j++) {
        int s = csr_src[j];
        float w = csr_w[j];
        float4 u = *(const float4*)&xw[(size_t)s * F_OUT + c];
        ax += w * u.x; ay += w * u.y; az += w * u.z; aw += w * u.w;
    }
    float4 b = *(const float4*)&bias[c];
    ax = fmaxf(ax + b.x, 0.f); ay = fmaxf(ay + b.y, 0.f);
    az = fmaxf(az + b.z, 0.f); aw = fmaxf(aw + b.w, 0.f);
    *(ushort4*)&out[(size_t)n * F_OUT + c] =
        make_ushort4(f2bf(ax), f2bf(ay), f2bf(az), f2bf(aw));
}

// ---------------- pooling ----------------
__global__ void k_gstart(const int* __restrict__ batch, int* gstart) {
    int g = threadIdx.x;
    if (g > N_GRAPHS) return;
    if (g == N_GRAPHS) { gstart[g] = N_NODES; return; }
    int lo = 0, hi = N_NODES;
    while (lo < hi) {
        int mid = (lo + hi) >> 1;
        if (batch[mid] < g) lo = mid + 1; else hi = mid;
    }
    gstart[g] = lo;
}

__global__ __launch_bounds__(64) void k_pool(const unsigned short* __restrict__ h,
                                             const int* __restrict__ gstart,
                                             float* __restrict__ out) {
    const int g = blockIdx.x;
    const int c = blockIdx.y * 256 + threadIdx.x * 4;
    const int lo = gstart[g], hi = gstart[g + 1];
    float ax = 0.f, ay = 0.f, az = 0.f, aw = 0.f;
    for (int n = lo; n < hi; n++) {
        ushort4 v = *(const ushort4*)&h[(size_t)n * F_OUT + c];
        ax += bf2f(v.x); ay += bf2f(v.y); az += bf2f(v.z); aw += bf2f(v.w);
    }
    float inv = 1.0f / (float)max(hi - lo, 1);
    *(float4*)&out[(size_t)g * F_OUT + c] = make_float4(ax * inv, ay * inv, az * inv, aw * inv);
}

// ---------------- launch ----------------
extern "C" void kernel_launch(void* const* d_in, const int* in_sizes, int n_in,
                              void* d_out, int out_size, void* d_ws, size_t ws_size,
                              hipStream_t stream) {
    const float* x    = (const float*)d_in[0];
    const int* ei     = (const int*)d_in[1];
    const float* ew   = (const float*)d_in[2];
    const int* batch  = (const int*)d_in[3];
    const float* W1   = (const float*)d_in[4];
    const float* b1   = (const float*)d_in[5];
    const float* W2   = (const float*)d_in[6];
    const float* b2   = (const float*)d_in[7];
    float* out = (float*)d_out;

    const int* src = ei;
    const int* dst = ei + N_EDGES;

    char* ws = (char*)d_ws;
    // region0 (phase A): xb | Wt1 | Wt2 | hb ; (phase B): h2 bf16 aliases offset 0
    const size_t SZ_XB  = (size_t)N_PAD * F_IN * 2;       // 20,578,304
    const size_t SZ_WT1 = (size_t)F_OUT * F_IN * 2;       //  1,048,576
    const size_t SZ_WT2 = (size_t)F_OUT * F_OUT * 2;      //  2,097,152
    const size_t SZ_HB  = (size_t)N_PAD * F_OUT * 2;      // 41,156,608
    unsigned short* xb  = (unsigned short*)(ws);
    unsigned short* Wt1 = (unsigned short*)(ws + SZ_XB);
    unsigned short* Wt2 = (unsigned short*)(ws + SZ_XB + SZ_WT1);
    unsigned short* hb  = (unsigned short*)(ws + SZ_XB + SZ_WT1 + SZ_WT2);
    unsigned short* h2  = (unsigned short*)(ws);          // aliases xb..Wt2 (dead in phase B)
    size_t off = SZ_XB + SZ_WT1 + SZ_WT2 + SZ_HB;
    auto alloc = [&](size_t bytes) -> void* {
        void* p = ws + off;
        off += (bytes + 255) & ~(size_t)255;
        return p;
    };
    float* xw     = (float*)alloc((size_t)N_PAD * F_OUT * 4);   // GEMM1 & GEMM2 output
    float* dinv   = (float*)alloc((size_t)N_NODES * 4);
    int*   cnt    = (int*)  alloc((size_t)N_NODES * 4);
    int*   offs   = (int*)  alloc((size_t)(N_NODES + 1) * 4);
    int*   cursor = (int*)  alloc((size_t)N_NODES * 4);
    int*   csrs   = (int*)  alloc((size_t)N_EDGES * 4);
    float* csrw   = (float*)alloc((size_t)N_EDGES * 4);
    int*   gstart = (int*)  alloc((size_t)(N_GRAPHS + 1) * 4);

    const int nb_n = (N_NODES + 255) / 256;
    const int nb_e = (N_EDGES + 255) / 256;

    k_init<<<nb_n, 256, 0, stream>>>(dinv, cnt, cursor);
    k_deg<<<nb_e, 256, 0, stream>>>(dst, ew, dinv, cnt);
    k_dinv<<<nb_n, 256, 0, stream>>>(dinv);
    k_scan<<<1, 1024, 0, stream>>>(cnt, offs);
    k_fill<<<nb_e, 256, 0, stream>>>(src, dst, ew, dinv, offs, cursor, csrs, csrw);
    k_gstart<<<1, 128, 0, stream>>>(batch, gstart);

    // conversions
    k_conv_x<<<(N_PAD * (F_IN / 8) + 255) / 256, 256, 0, stream>>>(x, xb);
    k_conv_wt<<<dim3(F_OUT / 32, F_IN / 32), 256, 0, stream>>>(W1, Wt1, F_IN);
    k_conv_wt<<<dim3(F_OUT / 32, F_OUT / 32), 256, 0, stream>>>(W2, Wt2, F_OUT);

    dim3 gg(N_PAD / 128, F_OUT / 128);
    // layer 1
    k_gemm_bf16<<<gg, 256, 0, stream>>>(xb, Wt1, xw, F_IN);
    k_aggr_bf16<<<N_PAD, 256, 0, stream>>>(xw, dinv, offs, csrs, csrw, b1, hb);
    // layer 2
    k_gemm_bf16<<<gg, 256, 0, stream>>>(hb, Wt2, xw, F_OUT);
    k_aggr_bf16<<<N_PAD, 256, 0, stream>>>(xw, dinv, offs, csrs, csrw, b2, h2);
    // pool
    dim3 gp(N_GRAPHS, F_OUT / 256);
    k_pool<<<gp, 64, 0, stream>>>(h2, gstart, out);
}

// Round 3
// 570.562 us; speedup vs baseline: 2.7421x; 1.3480x over previous
//
#include <hip/hip_runtime.h>

#define N_NODES 20000
#define N_PAD   20096   // next multiple of 128
#define N_EDGES 320000
#define F_IN 512
#define F_OUT 1024
#define N_GRAPHS 64

typedef __attribute__((ext_vector_type(8))) short bf16x8;
typedef __attribute__((ext_vector_type(4))) float f32x4;
typedef __attribute__((ext_vector_type(8))) unsigned short ushort8v;

static __device__ __forceinline__ unsigned short f2bf(float f) {
    unsigned int u = __float_as_uint(f);
    u = (u + 0x7fff + ((u >> 16) & 1)) >> 16;   // RNE
    return (unsigned short)u;
}
static __device__ __forceinline__ float bf2f(unsigned short s) {
    return __uint_as_float(((unsigned int)s) << 16);
}

// ---------------- degree / dinv ----------------
__global__ void k_init(float* deg, int* cnt, int* cursor) {
    int i = blockIdx.x * 256 + threadIdx.x;
    if (i < N_NODES) { deg[i] = 1.0f; cnt[i] = 0; cursor[i] = 0; }
}

__global__ void k_deg(const int* __restrict__ dst, const float* __restrict__ ew,
                      float* deg, int* cnt) {
    int e = blockIdx.x * 256 + threadIdx.x;
    if (e < N_EDGES) {
        int d = dst[e];
        atomicAdd(&deg[d], ew[e]);
        atomicAdd(&cnt[d], 1);
    }
}

__global__ void k_dinv(float* deg) {
    int i = blockIdx.x * 256 + threadIdx.x;
    if (i < N_NODES) deg[i] = rsqrtf(deg[i]);
}

// ---------------- CSR build ----------------
__global__ __launch_bounds__(1024) void k_scan(const int* __restrict__ cnt, int* offs) {
    __shared__ int s[1024];
    int t = threadIdx.x;
    const int CH = (N_NODES + 1023) / 1024;
    int lo = t * CH, hi = min(lo + CH, N_NODES);
    int sum = 0;
    for (int i = lo; i < hi; i++) sum += cnt[i];
    s[t] = sum;
    __syncthreads();
    for (int off = 1; off < 1024; off <<= 1) {
        int v = (t >= off) ? s[t - off] : 0;
        __syncthreads();
        s[t] += v;
        __syncthreads();
    }
    int run = (t == 0) ? 0 : s[t - 1];
    for (int i = lo; i < hi; i++) { offs[i] = run; run += cnt[i]; }
    if (hi == N_NODES && lo < N_NODES) offs[N_NODES] = run;
}

// packed (src, weight-as-bits) per edge
__global__ void k_fill(const int* __restrict__ src, const int* __restrict__ dst,
                       const float* __restrict__ ew, const float* __restrict__ dinv,
                       const int* __restrict__ offs, int* cursor,
                       int2* __restrict__ csre) {
    int e = blockIdx.x * 256 + threadIdx.x;
    if (e < N_EDGES) {
        int d = dst[e], s = src[e];
        int pos = offs[d] + atomicAdd(&cursor[d], 1);
        float w = dinv[s] * ew[e] * dinv[d];
        csre[pos] = make_int2(s, __float_as_int(w));
    }
}

// ---------------- conversions ----------------
__global__ void k_conv_x(const float* __restrict__ x, unsigned short* __restrict__ xb) {
    int idx = blockIdx.x * 256 + threadIdx.x;      // one thread = 8 cols
    int row = idx >> 6;                             // 64 chunks/row
    int c8 = (idx & 63) * 8;
    if (row >= N_PAD) return;
    ushort8v v;
    if (row < N_NODES) {
        const float* p = &x[(size_t)row * F_IN + c8];
#pragma unroll
        for (int i = 0; i < 8; i++) v[i] = f2bf(p[i]);
    } else {
#pragma unroll
        for (int i = 0; i < 8; i++) v[i] = 0;
    }
    *(ushort8v*)&xb[(size_t)row * F_IN + c8] = v;
}

// W [K][1024] f32 -> Wt [1024][K] bf16 (tiled transpose)
__global__ __launch_bounds__(256) void k_conv_wt(const float* __restrict__ W,
                                                 unsigned short* __restrict__ Wt, int K) {
    __shared__ float tile[32][33];
    int n0 = blockIdx.x * 32;
    int k0 = blockIdx.y * 32;
    int tx = threadIdx.x & 31;
    int ty = threadIdx.x >> 5;   // 0..7
#pragma unroll
    for (int i = 0; i < 32; i += 8)
        tile[ty + i][tx] = W[(size_t)(k0 + ty + i) * F_OUT + n0 + tx];
    __syncthreads();
#pragma unroll
    for (int i = 0; i < 32; i += 8)
        Wt[(size_t)(n0 + ty + i) * K + k0 + tx] = f2bf(tile[tx][ty + i]);
}

// ---------------- bf16 MFMA GEMM: C_bf16[Mpad,1024] = A[Mpad,K] @ Bt[1024,K]^T ----------------
__global__ __launch_bounds__(256) void k_gemm_bf16(const unsigned short* __restrict__ A,
                                                   const unsigned short* __restrict__ Bt,
                                                   unsigned short* __restrict__ C, int K) {
    __shared__ short As[128 * 32];
    __shared__ short Bs[128 * 32];
    const int tid = threadIdx.x;
    const int lane = tid & 63;
    const int wave = tid >> 6;
    const int wm = wave >> 1, wn = wave & 1;
    const int row0 = blockIdx.x * 128;
    const int col0 = blockIdx.y * 128;
    const int fl = lane & 15;
    const int fq = lane >> 4;

    f32x4 acc[4][4] = {};

    for (int k0 = 0; k0 < K; k0 += 32) {
#pragma unroll
        for (int it = 0; it < 2; it++) {
            int idx = it * 256 + tid;
            int r = idx >> 2, k8 = (idx & 3) * 8;
            const unsigned short* ga = &A[(size_t)(row0 + r) * K + k0 + k8];
            __builtin_amdgcn_global_load_lds(
                (const __attribute__((address_space(1))) void*)ga,
                (__attribute__((address_space(3))) void*)&As[idx * 8], 16, 0, 0);
            const unsigned short* gb = &Bt[(size_t)(col0 + r) * K + k0 + k8];
            __builtin_amdgcn_global_load_lds(
                (const __attribute__((address_space(1))) void*)gb,
                (__attribute__((address_space(3))) void*)&Bs[idx * 8], 16, 0, 0);
        }
        __syncthreads();

        bf16x8 af[4], bfr[4];
#pragma unroll
        for (int i = 0; i < 4; i++)
            af[i] = *(const bf16x8*)&As[(wm * 64 + i * 16 + fl) * 32 + fq * 8];
#pragma unroll
        for (int j = 0; j < 4; j++)
            bfr[j] = *(const bf16x8*)&Bs[(wn * 64 + j * 16 + fl) * 32 + fq * 8];
#pragma unroll
        for (int i = 0; i < 4; i++)
#pragma unroll
            for (int j = 0; j < 4; j++)
                acc[i][j] = __builtin_amdgcn_mfma_f32_16x16x32_bf16(af[i], bfr[j], acc[i][j], 0, 0, 0);
        __syncthreads();
    }

    // D layout: col = lane&15, row = quad*4 + reg
#pragma unroll
    for (int i = 0; i < 4; i++) {
#pragma unroll
        for (int j = 0; j < 4; j++) {
            int rbase = row0 + wm * 64 + i * 16 + fq * 4;
            int c = col0 + wn * 64 + j * 16 + fl;
#pragma unroll
            for (int r = 0; r < 4; r++)
                C[(size_t)(rbase + r) * F_OUT + c] = f2bf(acc[i][j][r]);
        }
    }
}

// ---------------- aggregation (bf16 in, bf16 out, fp32 accum) ----------------
// 128 threads/block, 1 node/block, 8 cols/thread (16B gather loads).
__global__ __launch_bounds__(128) void k_aggr_bf16(const unsigned short* __restrict__ xw,
                                                   const float* __restrict__ dinv,
                                                   const int* __restrict__ offs,
                                                   const int2* __restrict__ csre,
                                                   const float* __restrict__ bias,
                                                   unsigned short* __restrict__ out) {
    const int n = blockIdx.x;
    const int c = threadIdx.x * 8;
    if (n >= N_NODES) {   // zero pad rows (GEMM2 A-tile reads them)
        ushort8v z;
#pragma unroll
        for (int i = 0; i < 8; i++) z[i] = 0;
        *(ushort8v*)&out[(size_t)n * F_OUT + c] = z;
        return;
    }
    const float di = dinv[n];
    const float wself = di * di;

    float a[8];
    {
        ushort8v v = *(const ushort8v*)&xw[(size_t)n * F_OUT + c];
#pragma unroll
        for (int i = 0; i < 8; i++) a[i] = bf2f(v[i]) * wself;
    }

    const int lo = offs[n], hi = offs[n + 1];
    for (int j = lo; j < hi; j++) {
        int2 e = csre[j];
        float w = __int_as_float(e.y);
        ushort8v u = *(const ushort8v*)&xw[(size_t)e.x * F_OUT + c];
#pragma unroll
        for (int i = 0; i < 8; i++) a[i] += w * bf2f(u[i]);
    }
    float4 b0 = *(const float4*)&bias[c];
    float4 b1 = *(const float4*)&bias[c + 4];
    a[0] += b0.x; a[1] += b0.y; a[2] += b0.z; a[3] += b0.w;
    a[4] += b1.x; a[5] += b1.y; a[6] += b1.z; a[7] += b1.w;
    ushort8v r;
#pragma unroll
    for (int i = 0; i < 8; i++) r[i] = f2bf(fmaxf(a[i], 0.f));
    *(ushort8v*)&out[(size_t)n * F_OUT + c] = r;
}

// ---------------- pooling ----------------
__global__ void k_gstart(const int* __restrict__ batch, int* gstart) {
    int g = threadIdx.x;
    if (g > N_GRAPHS) return;
    if (g == N_GRAPHS) { gstart[g] = N_NODES; return; }
    int lo = 0, hi = N_NODES;
    while (lo < hi) {
        int mid = (lo + hi) >> 1;
        if (batch[mid] < g) lo = mid + 1; else hi = mid;
    }
    gstart[g] = lo;
}

__global__ __launch_bounds__(128) void k_pool(const unsigned short* __restrict__ h,
                                              const int* __restrict__ gstart,
                                              float* __restrict__ out) {
    const int g = blockIdx.x;
    const int c = blockIdx.y * 1024 + threadIdx.x * 8;  // 128 thr * 8 = full row
    const int lo = gstart[g], hi = gstart[g + 1];
    float a[8] = {};
    for (int n = lo; n < hi; n++) {
        ushort8v v = *(const ushort8v*)&h[(size_t)n * F_OUT + c];
#pragma unroll
        for (int i = 0; i < 8; i++) a[i] += bf2f(v[i]);
    }
    float inv = 1.0f / (float)max(hi - lo, 1);
    float4 r0 = make_float4(a[0] * inv, a[1] * inv, a[2] * inv, a[3] * inv);
    float4 r1 = make_float4(a[4] * inv, a[5] * inv, a[6] * inv, a[7] * inv);
    *(float4*)&out[(size_t)g * F_OUT + c] = r0;
    *(float4*)&out[(size_t)g * F_OUT + c + 4] = r1;
}

// ---------------- launch ----------------
extern "C" void kernel_launch(void* const* d_in, const int* in_sizes, int n_in,
                              void* d_out, int out_size, void* d_ws, size_t ws_size,
                              hipStream_t stream) {
    const float* x    = (const float*)d_in[0];
    const int* ei     = (const int*)d_in[1];
    const float* ew   = (const float*)d_in[2];
    const int* batch  = (const int*)d_in[3];
    const float* W1   = (const float*)d_in[4];
    const float* b1   = (const float*)d_in[5];
    const float* W2   = (const float*)d_in[6];
    const float* b2   = (const float*)d_in[7];
    float* out = (float*)d_out;

    const int* src = ei;
    const int* dst = ei + N_EDGES;

    char* ws = (char*)d_ws;
    const size_t SZ_XB  = (size_t)N_PAD * F_IN * 2;
    const size_t SZ_WT1 = (size_t)F_OUT * F_IN * 2;
    const size_t SZ_WT2 = (size_t)F_OUT * F_OUT * 2;
    const size_t SZ_B   = (size_t)N_PAD * F_OUT * 2;   // 41 MB bf16 feature buffer
    unsigned short* xb  = (unsigned short*)(ws);
    unsigned short* Wt1 = (unsigned short*)(ws + SZ_XB);
    unsigned short* Wt2 = (unsigned short*)(ws + SZ_XB + SZ_WT1);
    unsigned short* B1  = (unsigned short*)(ws + SZ_XB + SZ_WT1 + SZ_WT2);
    unsigned short* B2  = (unsigned short*)(ws + SZ_XB + SZ_WT1 + SZ_WT2 + SZ_B);
    size_t off = SZ_XB + SZ_WT1 + SZ_WT2 + 2 * SZ_B;
    auto alloc = [&](size_t bytes) -> void* {
        void* p = ws + off;
        off += (bytes + 255) & ~(size_t)255;
        return p;
    };
    float* dinv   = (float*)alloc((size_t)N_NODES * 4);
    int*   cnt    = (int*)  alloc((size_t)N_NODES * 4);
    int*   offs   = (int*)  alloc((size_t)(N_NODES + 1) * 4);
    int*   cursor = (int*)  alloc((size_t)N_NODES * 4);
    int2*  csre   = (int2*) alloc((size_t)N_EDGES * 8);
    int*   gstart = (int*)  alloc((size_t)(N_GRAPHS + 1) * 4);

    const int nb_n = (N_NODES + 255) / 256;
    const int nb_e = (N_EDGES + 255) / 256;

    k_init<<<nb_n, 256, 0, stream>>>(dinv, cnt, cursor);
    k_deg<<<nb_e, 256, 0, stream>>>(dst, ew, dinv, cnt);
    k_dinv<<<nb_n, 256, 0, stream>>>(dinv);
    k_scan<<<1, 1024, 0, stream>>>(cnt, offs);
    k_fill<<<nb_e, 256, 0, stream>>>(src, dst, ew, dinv, offs, cursor, csre);
    k_gstart<<<1, 128, 0, stream>>>(batch, gstart);

    // conversions
    k_conv_x<<<(N_PAD * (F_IN / 8) + 255) / 256, 256, 0, stream>>>(x, xb);
    k_conv_wt<<<dim3(F_OUT / 32, F_IN / 32), 256, 0, stream>>>(W1, Wt1, F_IN);
    k_conv_wt<<<dim3(F_OUT / 32, F_OUT / 32), 256, 0, stream>>>(W2, Wt2, F_OUT);

    dim3 gg(N_PAD / 128, F_OUT / 128);
    // layer 1: xb @ Wt1 -> B2 ; aggr -> B1
    k_gemm_bf16<<<gg, 256, 0, stream>>>(xb, Wt1, B2, F_IN);
    k_aggr_bf16<<<N_PAD, 128, 0, stream>>>(B2, dinv, offs, csre, b1, B1);
    // layer 2: B1 @ Wt2 -> B2 ; aggr -> B1
    k_gemm_bf16<<<gg, 256, 0, stream>>>(B1, Wt2, B2, F_OUT);
    k_aggr_bf16<<<N_PAD, 128, 0, stream>>>(B2, dinv, offs, csre, b2, B1);
    // pool
    dim3 gp(N_GRAPHS, 1);
    k_pool<<<gp, 128, 0, stream>>>(B1, gstart, out);
}